// Round 10
// baseline (268.397 us; speedup 1.0000x reference)
//
#include <hip/hip_runtime.h>
#include <hip/hip_bf16.h>
#include <math.h>

typedef __bf16 bf16x8 __attribute__((ext_vector_type(8)));
typedef float f32x4 __attribute__((ext_vector_type(4)));

#define CDIM 128

__global__ void sentinel_kernel(float* outf) {
  if (threadIdx.x == 0) outf[0] = 12345.0f;  // ws_size too small signature
}

// ---------------- prep + hist fused --------------------------------------
// blocks [0,48): wt[v][r][kb][o][j] = w_v[r][kb*8+j][o]
// block 48: c = le.e consts
// blocks [49,...): histogram over edges (deg pre-zeroed by memset)
__global__ __launch_bounds__(256) void prep_hist_kernel(
    const float* __restrict__ w1, const float* __restrict__ w2,
    __hip_bfloat16* __restrict__ wt,
    const float* __restrict__ le1, const float* __restrict__ e1,
    const float* __restrict__ le2, const float* __restrict__ e2,
    float* __restrict__ outc, const int* __restrict__ dstv,
    int* __restrict__ deg, int perW, int E) {
  const int b = blockIdx.x;
  const int tid = threadIdx.x;
  if (b < 48) {
    int t = b * 256 + tid;
    if (t >= perW * 2) return;
    const float* w = (t < perW) ? w1 : w2;
    int tt = (t < perW) ? t : t - perW;
    int r = tt >> 11;
    int rem = tt & 2047;
    int kb = rem >> 7;
    int o = rem & 127;
    const float* wr = w + ((size_t)r << 14);
    union { __hip_bfloat16 h[8]; int4 v; } u;
#pragma unroll
    for (int j = 0; j < 8; ++j)
      u.h[j] = __float2bfloat16(wr[(size_t)(kb * 8 + j) * CDIM + o]);
    *reinterpret_cast<int4*>(wt + (size_t)t * 8) = u.v;
  } else if (b == 48) {
    if (tid < 64) {
      float v1 = le1[tid] * e1[tid] + le1[tid + 64] * e1[tid + 64];
      float v2 = le2[tid] * e2[tid] + le2[tid + 64] * e2[tid + 64];
#pragma unroll
      for (int off = 32; off > 0; off >>= 1) {
        v1 += __shfl_xor(v1, off, 64);
        v2 += __shfl_xor(v2, off, 64);
      }
      if (tid == 0) { outc[0] = v1; outc[1] = v2; }
    }
  } else {
    int e = (b - 49) * 256 + tid;
    if (e < E) atomicAdd(&deg[dstv[e]], 1);
  }
}

// ---------------- single-pass scan (decoupled lookback, <=64 tiles) ----------
// tstate[i] = (value<<2) | flag;  flag: 0 invalid, 1 aggregate, 2 full prefix.
// All tiles co-resident (49 blocks << 256 CUs) -> spin-wait is safe.
__global__ __launch_bounds__(256) void scan_kernel(
    const int* __restrict__ deg, int* __restrict__ rowptr, int* __restrict__ cursor,
    int* __restrict__ tstate, int n, int E) {
  __shared__ int sh[256];
  __shared__ int shpref;
  const int tile = blockIdx.x;
  const int t = threadIdx.x;
  const int idx = tile * 1024 + t * 4;
  int v[4]; int s = 0;
#pragma unroll
  for (int j = 0; j < 4; ++j) { v[j] = (idx + j < n) ? deg[idx + j] : 0; s += v[j]; }
  sh[t] = s;
  __syncthreads();
  for (int off = 1; off < 256; off <<= 1) {
    int x = (t >= off) ? sh[t - off] : 0;
    __syncthreads();
    sh[t] += x;
    __syncthreads();
  }
  const int excl = sh[t] - s;
  const int agg = sh[255];
  if (t == 255)
    atomicExch(&tstate[tile], (tile == 0) ? ((agg << 2) | 2) : ((agg << 2) | 1));
  if (t == 0) {
    int prefix = 0;
    for (int j = tile - 1; j >= 0;) {
      int sv = atomicAdd(&tstate[j], 0);
      int st = sv & 3;
      if (st == 0) continue;       // not yet published; retry
      prefix += (sv >> 2);
      if (st == 2) break;          // full prefix found
      --j;                         // aggregate only; keep looking back
    }
    shpref = prefix;
  }
  __syncthreads();
  const int prefix = shpref;
  if (t == 255 && tile > 0)
    atomicExch(&tstate[tile], ((prefix + agg) << 2) | 2);
  int run = prefix + excl;
#pragma unroll
  for (int j = 0; j < 4; ++j) {
    if (idx + j < n) { rowptr[idx + j] = run; cursor[idx + j] = run; }
    run += v[j];
  }
  if (tile == 0 && t == 0) rowptr[n] = E;
}

__global__ __launch_bounds__(256) void scatter_kernel(
    const int* __restrict__ srcv, const int* __restrict__ dstv,
    const int* __restrict__ etype, const float* __restrict__ eattr,
    int* __restrict__ cursor, int2* __restrict__ kattr, int E, int n) {
  int e = blockIdx.x * 256 + threadIdx.x;
  if (e >= E) return;
  int p = atomicAdd(&cursor[dstv[e]], 1);
  kattr[p] = make_int2(etype[e] * n + srcv[e], __float_as_int(eattr[e]));
}

// ---------------- GEMM: all 3 relations per block; x read/decoded once --------
// xin_bf16: input activations already bf16 (conv2 reading h) vs f32 (conv1).
__global__ __launch_bounds__(256) void gemm_xw_kernel(
    const void* __restrict__ xin, int xin_bf16,
    const __hip_bfloat16* __restrict__ wt,
    const float* __restrict__ qv, const float* __restrict__ kv,
    __hip_bfloat16* __restrict__ xwout, float* __restrict__ sq, float* __restrict__ sk,
    int n) {
  __shared__ __hip_bfloat16 wlds[16 * 128 * 8];  // 32 KB
  const int base = blockIdx.x * 128;
  const int tid = threadIdx.x;
  const int wave = tid >> 6, lane = tid & 63;
  const int quad = lane >> 4, c16 = lane & 15;

  bf16x8 zf;
#pragma unroll
  for (int j = 0; j < 8; ++j) zf[j] = (__bf16)0.0f;

  // A fragments: load (+convert if f32) once, reused for all 3 relations
  bf16x8 af[2][4];
#pragma unroll
  for (int h = 0; h < 2; ++h) {
    int m = base + wave * 32 + h * 16 + c16;
#pragma unroll
    for (int ks = 0; ks < 4; ++ks) {
      if (m < n) {
        size_t off = (size_t)m * CDIM + ks * 32 + quad * 8;
        if (xin_bf16) {
          af[h][ks] = *reinterpret_cast<const bf16x8*>((const __hip_bfloat16*)xin + off);
        } else {
          const float* xp = (const float*)xin + off;
          f32x4 x0 = *reinterpret_cast<const f32x4*>(xp);
          f32x4 x1 = *reinterpret_cast<const f32x4*>(xp + 4);
          bf16x8 a;
#pragma unroll
          for (int j = 0; j < 4; ++j) { a[j] = (__bf16)x0[j]; a[4 + j] = (__bf16)x1[j]; }
          af[h][ks] = a;
        }
      } else {
        af[h][ks] = zf;
      }
    }
  }

  float qf[8], kf[8];
#pragma unroll
  for (int nt = 0; nt < 8; ++nt) {
    qf[nt] = qv[nt * 16 + c16];
    kf[nt] = kv[nt * 16 + c16];
  }

  for (int r = 0; r < 3; ++r) {
    if (r) __syncthreads();  // previous r's LDS reads done (epilogue passed)
    {
      const int4* src = reinterpret_cast<const int4*>(wt + ((size_t)r << 14));
      int4* dst = reinterpret_cast<int4*>(wlds);
      for (int i = tid; i < 2048; i += 256) dst[i] = src[i];
    }
    __syncthreads();

    f32x4 acc[2][8];
#pragma unroll
    for (int h = 0; h < 2; ++h)
#pragma unroll
      for (int nt = 0; nt < 8; ++nt) acc[h][nt] = (f32x4){0.f, 0.f, 0.f, 0.f};

#pragma unroll
    for (int ks = 0; ks < 4; ++ks) {
#pragma unroll
      for (int nt = 0; nt < 8; ++nt) {
        bf16x8 b = *reinterpret_cast<const bf16x8*>(
            &wlds[(((ks * 4 + quad) * 128) + nt * 16 + c16) * 8]);
        acc[0][nt] = __builtin_amdgcn_mfma_f32_16x16x32_bf16(af[0][ks], b, acc[0][nt], 0, 0, 0);
        acc[1][nt] = __builtin_amdgcn_mfma_f32_16x16x32_bf16(af[1][ks], b, acc[1][nt], 0, 0, 0);
      }
    }

#pragma unroll
    for (int h = 0; h < 2; ++h) {
      int rowb = base + wave * 32 + h * 16 + quad * 4;
#pragma unroll
      for (int reg = 0; reg < 4; ++reg) {
        int grow = rowb + reg;
        float s_q = 0.f, s_k = 0.f;
#pragma unroll
        for (int nt = 0; nt < 8; ++nt) {
          float v = acc[h][nt][reg];
          if (grow < n)
            xwout[(((size_t)r * n + grow) << 7) + nt * 16 + c16] = __float2bfloat16(v);
          s_q += v * qf[nt];
          s_k += v * kf[nt];
        }
#pragma unroll
        for (int off = 1; off < 16; off <<= 1) {
          s_q += __shfl_xor(s_q, off, 64);
          s_k += __shfl_xor(s_k, off, 64);
        }
        if (c16 == 0 && grow < n) {
          sq[r * n + grow] = s_q;
          sk[r * n + grow] = s_k;
        }
      }
    }
  }
}

// ---------------- aggregation: single pass, no max-subtraction, no LDS --------
// out_bf16: conv1 hidden stored bf16 (feeds gemm2); else f32 to d_out.
__global__ __launch_bounds__(256) void aggregate_kernel(
    const int* __restrict__ rowptr, const int2* __restrict__ kattr,
    const float* __restrict__ sq, const float* __restrict__ sk,
    const __hip_bfloat16* __restrict__ xw, const float* __restrict__ bias,
    const float* __restrict__ cscal, void* __restrict__ out, int n,
    int do_relu, int out_bf16) {
  const int wave = threadIdx.x >> 6, lane = threadIdx.x & 63;
  const int node = blockIdx.x * 4 + wave;
  if (node >= n) return;
  const int g = lane >> 4;     // edge group
  const int sub = lane & 15;   // 8-col chunk
  const float c = cscal[0];
  const int n2 = n * 2;

  const int start = rowptr[node];
  const int deg = rowptr[node + 1] - start;
  const float s0 = sq[node], s1 = sq[n + node], s2 = sq[n2 + node];

  float acc[8];
#pragma unroll
  for (int t = 0; t < 8; ++t) acc[t] = 0.f;
  float den = 0.f;

  for (int j0 = 0; j0 < deg; j0 += 4) {
    int j = j0 + g;
    if (j < deg) {
      int2 ka = kattr[start + j];          // broadcast within group
      int kk = ka.x;
      float sv = (kk >= n2) ? s2 : ((kk >= n) ? s1 : s0);
      float l = sv + sk[kk] + c * __int_as_float(ka.y);   // sk: broadcast
      l = l > 0.f ? l : 0.2f * l;
      float w = __expf(l);
      bf16x8 f = *reinterpret_cast<const bf16x8*>(xw + ((size_t)kk << 7) + sub * 8);
#pragma unroll
      for (int t = 0; t < 8; ++t) acc[t] += w * (float)f[t];
      den += w;
    }
  }

#pragma unroll
  for (int t = 0; t < 8; ++t) {
    acc[t] += __shfl_xor(acc[t], 16, 64);
    acc[t] += __shfl_xor(acc[t], 32, 64);
  }
  den += __shfl_xor(den, 16, 64);
  den += __shfl_xor(den, 32, 64);

  if (g == 0) {
    float inv = 1.0f / (den + 1e-16f);
    f32x4 b0 = *reinterpret_cast<const f32x4*>(bias + sub * 8);
    f32x4 b1 = *reinterpret_cast<const f32x4*>(bias + sub * 8 + 4);
    f32x4 o0, o1;
#pragma unroll
    for (int t = 0; t < 4; ++t) {
      o0[t] = acc[t] * inv + b0[t];
      o1[t] = acc[4 + t] * inv + b1[t];
    }
    if (do_relu) {
#pragma unroll
      for (int t = 0; t < 4; ++t) {
        o0[t] = fmaxf(o0[t], 0.f);
        o1[t] = fmaxf(o1[t], 0.f);
      }
    }
    if (out_bf16) {
      bf16x8 ob;
#pragma unroll
      for (int t = 0; t < 4; ++t) { ob[t] = (__bf16)o0[t]; ob[4 + t] = (__bf16)o1[t]; }
      *reinterpret_cast<bf16x8*>((__hip_bfloat16*)out + (size_t)node * CDIM + sub * 8) = ob;
    } else {
      float* op = (float*)out + (size_t)node * CDIM + sub * 8;
      *reinterpret_cast<f32x4*>(op) = o0;
      *reinterpret_cast<f32x4*>(op + 4) = o1;
    }
  }
}

// ---------------- launcher ----------------

extern "C" void kernel_launch(void* const* d_in, const int* in_sizes, int n_in,
                              void* d_out, int out_size, void* d_ws, size_t ws_size,
                              hipStream_t stream) {
  const float* x     = (const float*)d_in[0];
  const int*   eidx  = (const int*)d_in[1];
  const int*   etype = (const int*)d_in[2];
  const float* eattr = (const float*)d_in[3];
  const float* w1  = (const float*)d_in[4];
  const float* q1  = (const float*)d_in[5];
  const float* k1  = (const float*)d_in[6];
  const float* le1 = (const float*)d_in[7];
  const float* e1  = (const float*)d_in[8];
  const float* b1  = (const float*)d_in[9];
  const float* w2  = (const float*)d_in[10];
  const float* q2  = (const float*)d_in[11];
  const float* k2  = (const float*)d_in[12];
  const float* le2 = (const float*)d_in[13];
  const float* e2  = (const float*)d_in[14];
  const float* b2  = (const float*)d_in[15];

  const int N = in_sizes[0] / CDIM;           // 50000
  const int E = in_sizes[2];                  // 500000
  const int R = in_sizes[4] / (CDIM * CDIM);  // 3
  const int* srcv = eidx;
  const int* dstv = eidx + E;

  char* p = (char*)d_ws;
  auto alloc = [&](size_t bytes) -> void* {
    void* q = (void*)p;
    p += (bytes + 255) & ~(size_t)255;
    return q;
  };
  float* sq       = (float*)alloc((size_t)R * N * 4);
  float* sk       = (float*)alloc((size_t)R * N * 4);
  int*   deg      = (int*)alloc((size_t)N * 4);
  int*   tstate   = (int*)alloc(256);          // contiguous with deg for one memset
  int*   rowptr   = (int*)alloc((size_t)(N + 1) * 4);
  int*   cursor   = (int*)alloc((size_t)N * 4);
  int2*  kattr    = (int2*)alloc((size_t)E * 8);
  __hip_bfloat16* wt = (__hip_bfloat16*)alloc((size_t)2 * R * CDIM * CDIM * 2);
  float* cscal    = (float*)alloc(256);
  __hip_bfloat16* xw = (__hip_bfloat16*)alloc((size_t)R * N * CDIM * 2);
  size_t base_need = (size_t)(p - (char*)d_ws);
  __hip_bfloat16* hb = (__hip_bfloat16*)alloc((size_t)N * CDIM * 2);
  size_t h_need = (size_t)(p - (char*)d_ws);

  if (base_need > ws_size) {
    sentinel_kernel<<<1, 64, 0, stream>>>((float*)d_out);
    return;
  }
  const int use_bf16_h = (h_need <= ws_size) ? 1 : 0;

  float* outp = (float*)d_out;
  // conv1 hidden: bf16 in ws if it fits, else f32 in d_out (dead before final write)
  void* hbuf = use_bf16_h ? (void*)hb : (void*)outp;

  const int eg = (E + 255) / 256;
  const int nb = (N + 1023) / 1024;           // 49 tiles (<=64 for lookback + co-residency)
  const int nodes4 = (N + 3) / 4;
  const int perW = R * 2048;

  // zero deg + tstate in one fill (contiguous allocs)
  hipMemsetAsync(deg, 0, (size_t)((char*)tstate - (char*)deg) + 256, stream);

  prep_hist_kernel<<<49 + eg, 256, 0, stream>>>(w1, w2, wt, le1, e1, le2, e2,
                                                cscal, dstv, deg, perW, E);
  scan_kernel<<<nb, 256, 0, stream>>>(deg, rowptr, cursor, tstate, N, E);
  scatter_kernel<<<eg, 256, 0, stream>>>(srcv, dstv, etype, eattr, cursor, kattr, E, N);

  dim3 ggrid((N + 127) / 128);

  // ---- conv1 ----
  gemm_xw_kernel<<<ggrid, 256, 0, stream>>>(x, 0, wt, q1, k1, xw, sq, sk, N);
  aggregate_kernel<<<nodes4, 256, 0, stream>>>(rowptr, kattr, sq, sk, xw, b1,
                                               cscal + 0, hbuf, N, 1, use_bf16_h);

  // ---- conv2 ----
  gemm_xw_kernel<<<ggrid, 256, 0, stream>>>(hbuf, use_bf16_h,
                                            wt + (size_t)R * CDIM * CDIM,
                                            q2, k2, xw, sq, sk, N);
  aggregate_kernel<<<nodes4, 256, 0, stream>>>(rowptr, kattr, sq, sk, xw, b2,
                                               cscal + 1, outp, N, 0, 0);
}